// Round 8
// baseline (4487.393 us; speedup 1.0000x reference)
//
#include <hip/hip_runtime.h>
#include <stdint.h>

// Problem constants: B=2048, S=512, F=64, H=256
#define SEQ   512
#define FD    64
#define HD    256
#define ZSTR  324            // bf16 elems per Z row; 162 words % 8 == 2 (conflict-free b128 + cheap scalar writes)
#define CSTR  260            // 130 words % 8 == 2

// ws layout: per wave-role w (0..7): 16 groups x 5 chunks x 1KB = 80KB of gate weights,
// in consumption order. Group i of wave w: p=i>>3, h=(i>>2)&1, nt=i&3 (h-major inside p
// so the consumer holds only 5 A-frags at a time). Rows n = nt*256 + (2w+p)*16 + (l&15),
// k = h*160 + c*32 + (l>>4)*8 + e; chunk byte = lane*16.
// Dense W after at byte 655360: 4 roles x 8 chunks x 1KB.
#define GRPB      5120
#define WGB       (16 * GRPB)      // 81920 B per wave-role
#define DENSE_OFF (8 * WGB)        // 655360 B
#define RING_D    3                // ring slots per wave (issue leads consumption by 2)

typedef __attribute__((ext_vector_type(8))) __bf16 bf16x8;
typedef __attribute__((ext_vector_type(4))) float  f32x4;

__device__ __forceinline__ float sigm(float x) {
    return __builtin_amdgcn_rcpf(1.0f + __expf(-x));
}
__device__ __forceinline__ float tanh_(float x) {
    return 2.0f * __builtin_amdgcn_rcpf(1.0f + __expf(-2.0f * x)) - 1.0f;
}

// async global->LDS DMA, 16B per lane (dest = wave-uniform base + lane*16; no VGPR round trip)
__device__ __forceinline__ void dma16(const void* g, void* l) {
    __builtin_amdgcn_global_load_lds(
        (const __attribute__((address_space(1))) int*)g,
        (__attribute__((address_space(3))) int*)l, 16, 0, 0);
}

// ---------------- prep: fp32 weights -> bf16 fragment chunks in ws ----------------
__global__ __launch_bounds__(64) void prep_weights(
    const float* __restrict__ W_ih, const float* __restrict__ W_hh,
    const float* __restrict__ W_dense, __bf16* __restrict__ wsb)
{
    const int b = blockIdx.x, l = threadIdx.x, lr = l & 15, lg = l >> 4;
    if (b < 128) {
        const int w = b >> 4, i = b & 15;
        const int s = 2 * w + (i >> 3), h = (i >> 2) & 1, nt = i & 3;
        const int n = nt * 256 + s * 16 + lr;
        for (int c = 0; c < 5; ++c) {
            const int k0 = h * 160 + c * 32 + lg * 8;
            const float* src = (k0 < 64) ? (W_ih + n * 64 + k0)
                                         : (W_hh + n * 256 + (k0 - 64));
            bf16x8 v;
            for (int e = 0; e < 8; ++e) v[e] = (__bf16)src[e];
            *(bf16x8*)(wsb + (size_t)((w * 16 + i) * 5 + c) * 512 + l * 8) = v;
        }
    } else {
        const int d = b - 128;          // dense role 0..3
        const int f = d * 16 + lr;
        for (int c = 0; c < 8; ++c) {
            const float* src = W_dense + f * 256 + c * 32 + lg * 8;
            bf16x8 v;
            for (int e = 0; e < 8; ++e) v[e] = (__bf16)src[e];
            *(bf16x8*)(wsb + DENSE_OFF / 2 + d * 4096 + c * 512 + l * 8) = v;
        }
    }
}

// ---------------- main persistent LSTM kernel ----------------
// 128 blocks x 512 threads (8 waves, 1 block/CU). ALL gate weights stream every step
// through a per-wave LDS ring via global_load_lds. Counted vmcnt discipline requires
// that OUR DMAs are the only vmem ops inside the idx loop -> register pressure kept
// ~110 arch VGPRs (aph[5] phase A-frags instead of a[10]; dense W re-loaded per step)
// so no scratch spills can corrupt the count (R7's failure).
__global__ __launch_bounds__(512) __attribute__((amdgpu_waves_per_eu(2, 2)))
void lstm_persist(
    const float* __restrict__ h0, const float* __restrict__ c0,
    const float* __restrict__ b_ih, const float* __restrict__ b_hh,
    const float* __restrict__ b_dense, const __bf16* __restrict__ wsb,
    float* __restrict__ out)
{
    __shared__ __align__(1024) char  RING[8 * RING_D * GRPB];  // 122,880 B
    __shared__ __align__(16) __bf16 Zb[2 * 16 * ZSTR];         //  20,736 B
    __shared__ __align__(16) __bf16 CBb[16 * CSTR];            //   8,320 B

    const int tid = threadIdx.x;
    const int w   = tid >> 6;
    const int l   = tid & 63;
    const int lr  = l & 15;
    const int lg  = l >> 4;
    const int row0 = blockIdx.x * 16;

    const char*   wgbase = (const char*)wsb + (size_t)w * WGB;
    char*         ringw  = RING + w * (RING_D * GRPB);
    const __bf16* wdbase = wsb + DENSE_OFF / 2 + w * 4096 + l * 8;  // dense chunks (w<4)

    // ---- biases, initial state ----
    float biasv[2][4];
    float creg[2][4];
#pragma unroll
    for (int p = 0; p < 2; ++p) {
        const int jj = (2 * w + p) * 16 + lr;
#pragma unroll
        for (int nt = 0; nt < 4; ++nt) {
            const int n = nt * 256 + jj;
            biasv[p][nt] = b_ih[n] + b_hh[n];
        }
#pragma unroll
        for (int r = 0; r < 4; ++r)
            creg[p][r] = c0[(size_t)(row0 + lg * 4 + r) * HD + jj];
    }
    float ybias = (w < 4) ? b_dense[w * 16 + lr] : 0.0f;

    // ---- stage h0 into Z0 h-part (512 threads x 8 elems) ----
    {
        const int e0 = tid * 8;
        const int m  = e0 >> 8;
        const int jj = e0 & 255;
        const float4 h1 = *(const float4*)(h0 + (size_t)(row0 + m) * HD + jj);
        const float4 h2 = *(const float4*)(h0 + (size_t)(row0 + m) * HD + jj + 4);
        __bf16* zp = &Zb[m * ZSTR + 64 + jj];
        zp[0] = (__bf16)h1.x; zp[1] = (__bf16)h1.y; zp[2] = (__bf16)h1.z; zp[3] = (__bf16)h1.w;
        zp[4] = (__bf16)h2.x; zp[5] = (__bf16)h2.y; zp[6] = (__bf16)h2.z; zp[7] = (__bf16)h2.w;
    }
    __syncthreads();

    // ---- x_0 = dense(h0) -> Z0 x-part ----
    if (w < 4) {
        f32x4 ya = {ybias, ybias, ybias, ybias};
#pragma unroll
        for (int c = 0; c < 8; ++c) {
            bf16x8 wdc = *(const bf16x8*)(wdbase + c * 512);
            bf16x8 av  = *(const bf16x8*)(&Zb[lr * ZSTR + 64 + c * 32 + lg * 8]);
            ya = __builtin_amdgcn_mfma_f32_16x16x32_bf16(av, wdc, ya, 0, 0, 0);
        }
#pragma unroll
        for (int r = 0; r < 4; ++r)
            Zb[(lg * 4 + r) * ZSTR + w * 16 + lr] = (__bf16)ya[r];
    }

    float* outp = out + (size_t)row0 * SEQ * FD;

    // ---------------- 512-step recurrence ----------------
    for (int t = 0; t < SEQ; ++t) {
        __syncthreads();   // barrier A: Z[cur] complete; drains ALL vmem -> vmcnt ledger = 0

        const __bf16* Zc = Zb + (t & 1) * (16 * ZSTR);
        __bf16*       Zn = Zb + ((t + 1) & 1) * (16 * ZSTR);

        // marching per-lane global pointer over this wave's 80 chunks (laundered so
        // nothing is hoisted out of the t-loop).
        const char* gp = wgbase + (size_t)l * 16;
        asm volatile("" : "+v"(gp));

        // prologue: issue groups 0,1 into ring slots 0,1
#pragma unroll
        for (int c = 0; c < 10; ++c) {
            dma16(gp, ringw + (c / 5) * GRPB + (c % 5) * 1024);
            gp += 1024;
        }

        bf16x8 aph[5];     // A-frags for the current (p,h) phase only
        f32x4  acc[4];

#pragma unroll
        for (int i = 0; i < 16; ++i) {
            const int p = i >> 3, h = (i >> 2) & 1, nt = i & 3;

            // phase start: (re)load the 5 A-frags for this k-half
            if ((i & 3) == 0) {
#pragma unroll
                for (int c = 0; c < 5; ++c)
                    aph[c] = *(const bf16x8*)(&Zc[lr * ZSTR + (h * 5 + c) * 32 + lg * 8]);
            }

            // issue group i+2 (slot (i+2)%3: its last reads retired one group ago)
            if (i + 2 < 16) {
#pragma unroll
                for (int c = 0; c < 5; ++c) {
                    dma16(gp, ringw + ((i + 2) % 3) * GRPB + c * 1024);
                    gp += 1024;
                }
            }

            // counted wait: group i's 5 DMAs landed; up to 2 newer groups in flight
            if (i <= 13)      asm volatile("s_waitcnt vmcnt(10)" ::: "memory");
            else if (i == 14) asm volatile("s_waitcnt vmcnt(5)"  ::: "memory");
            else              asm volatile("s_waitcnt vmcnt(0)"  ::: "memory");
            __builtin_amdgcn_sched_barrier(0);

            // read the group's 5 B-chunks from the ring (conflict-free: lane*16B)
            const char* slot = ringw + (i % 3) * GRPB;
            bf16x8 b0 = *(const bf16x8*)(slot + 0 * 1024 + l * 16);
            bf16x8 b1 = *(const bf16x8*)(slot + 1 * 1024 + l * 16);
            bf16x8 b2 = *(const bf16x8*)(slot + 2 * 1024 + l * 16);
            bf16x8 b3 = *(const bf16x8*)(slot + 3 * 1024 + l * 16);
            bf16x8 b4 = *(const bf16x8*)(slot + 4 * 1024 + l * 16);

            const float bb = biasv[p][nt];
            f32x4 cc = (h == 0) ? f32x4{bb, bb, bb, bb} : acc[nt];
            cc = __builtin_amdgcn_mfma_f32_16x16x32_bf16(aph[0], b0, cc, 0, 0, 0);
            cc = __builtin_amdgcn_mfma_f32_16x16x32_bf16(aph[1], b1, cc, 0, 0, 0);
            cc = __builtin_amdgcn_mfma_f32_16x16x32_bf16(aph[2], b2, cc, 0, 0, 0);
            cc = __builtin_amdgcn_mfma_f32_16x16x32_bf16(aph[3], b3, cc, 0, 0, 0);
            cc = __builtin_amdgcn_mfma_f32_16x16x32_bf16(aph[4], b4, cc, 0, 0, 0);
            acc[nt] = cc;

            if ((i & 7) == 7) {
                // element-wise LSTM update for slice p (gates i,f,g,o complete)
                const int jj = (2 * w + p) * 16 + lr;
#pragma unroll
                for (int r = 0; r < 4; ++r) {
                    const int m = lg * 4 + r;
                    const float ig = sigm(acc[0][r]);
                    const float fg = sigm(acc[1][r]);
                    const float gg = tanh_(acc[2][r]);
                    const float og = sigm(acc[3][r]);
                    const float cn = fg * creg[p][r] + ig * gg;
                    creg[p][r] = cn;
                    const float hn = og * tanh_(cn);
                    Zn[m * ZSTR + 64 + jj] = (__bf16)hn;
                    CBb[m * CSTR + jj]     = (__bf16)cn;
                }
            }
        }

        __syncthreads();   // barrier B: CB ready

        if (w < 4) {
            // y_t = c_new @ W_dense^T + b_dense. Dense W re-loaded from L2 every step
            // (laundered: persistent wd[] would re-inflate pressure -> spills, R7's bug).
            const __bf16* wdp = wdbase;
            asm volatile("" : "+v"(wdp));
            f32x4 ya = {ybias, ybias, ybias, ybias};
#pragma unroll
            for (int c = 0; c < 8; ++c) {
                bf16x8 wdc = *(const bf16x8*)(wdp + c * 512);
                bf16x8 acb = *(const bf16x8*)(&CBb[lr * CSTR + c * 32 + lg * 8]);
                ya = __builtin_amdgcn_mfma_f32_16x16x32_bf16(acb, wdc, ya, 0, 0, 0);
            }
            const int f = w * 16 + lr;
#pragma unroll
            for (int r = 0; r < 4; ++r) {
                const int m = lg * 4 + r;
                outp[(size_t)m * (SEQ * FD) + t * FD + f] = ya[r];  // fp32 output
                Zn[m * ZSTR + f] = (__bf16)ya[r];                   // x for next step
            }
        }
    }
}

extern "C" void kernel_launch(void* const* d_in, const int* in_sizes, int n_in,
                              void* d_out, int out_size, void* d_ws, size_t ws_size,
                              hipStream_t stream) {
    (void)in_sizes; (void)n_in; (void)ws_size; (void)out_size;
    const float* h0      = (const float*)d_in[1];
    const float* c0      = (const float*)d_in[2];
    const float* W_ih    = (const float*)d_in[3];
    const float* W_hh    = (const float*)d_in[4];
    const float* b_ih    = (const float*)d_in[5];
    const float* b_hh    = (const float*)d_in[6];
    const float* W_dense = (const float*)d_in[7];
    const float* b_dense = (const float*)d_in[8];
    __bf16* wsb = (__bf16*)d_ws;    // uses 687,104 bytes of workspace

    prep_weights<<<132, 64, 0, stream>>>(W_ih, W_hh, W_dense, wsb);
    lstm_persist<<<128, 512, 0, stream>>>(h0, c0, b_ih, b_hh, b_dense, wsb, (float*)d_out);
}

// Round 9
// 3568.621 us; speedup vs baseline: 1.2575x; 1.2575x over previous
//
#include <hip/hip_runtime.h>
#include <stdint.h>

// Problem constants: B=2048, S=512, F=64, H=256
#define SEQ   512
#define FD    64
#define HD    256
#define ZSTR  324            // bf16 elems per Z row; 162 words % 8 == 2 (conflict-free b128, <=2-way scalar writes)
#define CSTR  260            // 130 words % 8 == 2

// ws layout (prep writes, main reads): 16 wave-roles w (one 16-col j-slice each).
// Per role: 8 groups (h=i>>2, nt=i&3) x 5 chunks x 1KB, in consumption order.
// Chunk = 64 lanes x 16B, exact B-fragment order: lane l holds
//   W[n = nt*256 + w*16 + (l&15)][k = h*160 + c*32 + (l>>4)*8 + e], e=0..7.
// Dense W at DENSE_OFF: 4 roles x 8 chunks x 1KB.
#define GRPB      5120
#define WGB       (8 * GRPB)         // 40,960 B per wave-role
#define DENSE_OFF (16 * WGB)         // 655,360 B
typedef __attribute__((ext_vector_type(8))) __bf16 bf16x8;
typedef __attribute__((ext_vector_type(4))) float  f32x4;

__device__ __forceinline__ float sigm(float x) {
    return __builtin_amdgcn_rcpf(1.0f + __expf(-x));
}
__device__ __forceinline__ float tanh_(float x) {
    return 2.0f * __builtin_amdgcn_rcpf(1.0f + __expf(-2.0f * x)) - 1.0f;
}

// ---------------- prep: fp32 weights -> bf16 fragment chunks in ws ----------------
__global__ __launch_bounds__(64) void prep_weights(
    const float* __restrict__ W_ih, const float* __restrict__ W_hh,
    const float* __restrict__ W_dense, __bf16* __restrict__ wsb)
{
    const int b = blockIdx.x, l = threadIdx.x, lr = l & 15, lg = l >> 4;
    if (b < 128) {
        const int w = b >> 3, i = b & 7;        // role 0..15, group 0..7
        const int h = (i >> 2) & 1, nt = i & 3;
        const int n = nt * 256 + w * 16 + lr;
        for (int c = 0; c < 5; ++c) {
            const int k0 = h * 160 + c * 32 + lg * 8;
            const float* src = (k0 < 64) ? (W_ih + n * 64 + k0)
                                         : (W_hh + n * 256 + (k0 - 64));
            bf16x8 v;
            for (int e = 0; e < 8; ++e) v[e] = (__bf16)src[e];
            *(bf16x8*)(wsb + (size_t)(b * 5 + c) * 512 + l * 8) = v;
        }
    } else {
        const int d = b - 128;          // dense role 0..3
        const int f = d * 16 + lr;
        for (int c = 0; c < 8; ++c) {
            const float* src = W_dense + f * 256 + c * 32 + lg * 8;
            bf16x8 v;
            for (int e = 0; e < 8; ++e) v[e] = (__bf16)src[e];
            *(bf16x8*)(wsb + DENSE_OFF / 2 + d * 4096 + c * 512 + l * 8) = v;
        }
    }
}

// ---------------- main persistent LSTM kernel ----------------
// 128 blocks x 1024 threads (16 waves, 4/SIMD). Each wave owns ONE 16-col j-slice
// (all 4 gates) and streams its 8 weight groups L2 -> VGPR with a 2-group register
// double-buffer. NO manual vmcnt (compiler scoreboard orders loads -> correctness by
// construction), NO LDS weight staging (R8: LDS-BW bound), NO resident weight class
// (R3-R6: allocator remats anything over the 128-VGPR cap). Live set ~105 VGPR < cap.
__global__ __launch_bounds__(1024, 4) void lstm_persist(
    const float* __restrict__ h0, const float* __restrict__ c0,
    const float* __restrict__ b_ih, const float* __restrict__ b_hh,
    const float* __restrict__ b_dense, const __bf16* __restrict__ wsb,
    float* __restrict__ out)
{
    __shared__ __align__(16) __bf16 Zb[2 * 16 * ZSTR];   // 20,736 B
    __shared__ __align__(16) __bf16 CBb[16 * CSTR];      //  8,320 B

    const int tid = threadIdx.x;
    const int w   = tid >> 6;       // wave 0..15 = j-slice role
    const int l   = tid & 63;
    const int lr  = l & 15;
    const int lg  = l >> 4;
    const int row0 = blockIdx.x * 16;
    const int jj  = w * 16 + lr;    // hidden column owned by this lane

    const __bf16* wgbase = wsb + (size_t)w * (WGB / 2);              // this wave's 8 groups
    const __bf16* wdbase = wsb + DENSE_OFF / 2 + w * 4096 + l * 8;   // dense chunks (w<4)

    // ---- biases, initial state (one slice per wave) ----
    float biasv[4];
    float creg[4];
#pragma unroll
    for (int nt = 0; nt < 4; ++nt) {
        const int n = nt * 256 + jj;
        biasv[nt] = b_ih[n] + b_hh[n];
    }
#pragma unroll
    for (int r = 0; r < 4; ++r)
        creg[r] = c0[(size_t)(row0 + lg * 4 + r) * HD + jj];
    float ybias = (w < 4) ? b_dense[w * 16 + lr] : 0.0f;

    // ---- stage h0 into Z0 h-part (1024 threads x 4 elems) ----
    {
        const int e0 = tid * 4;
        const int m  = e0 >> 8;
        const int j4 = e0 & 255;
        const float4 hv = *(const float4*)(h0 + (size_t)(row0 + m) * HD + j4);
        __bf16* zp = &Zb[m * ZSTR + 64 + j4];
        zp[0] = (__bf16)hv.x; zp[1] = (__bf16)hv.y;
        zp[2] = (__bf16)hv.z; zp[3] = (__bf16)hv.w;
    }
    __syncthreads();

    // ---- x_0 = dense(h0) -> Z0 x-part ----
    if (w < 4) {
        f32x4 ya = {ybias, ybias, ybias, ybias};
#pragma unroll
        for (int c = 0; c < 8; ++c) {
            bf16x8 wdc = *(const bf16x8*)(wdbase + c * 512);
            bf16x8 av  = *(const bf16x8*)(&Zb[lr * ZSTR + 64 + c * 32 + lg * 8]);
            ya = __builtin_amdgcn_mfma_f32_16x16x32_bf16(av, wdc, ya, 0, 0, 0);
        }
#pragma unroll
        for (int r = 0; r < 4; ++r)
            Zb[(lg * 4 + r) * ZSTR + w * 16 + lr] = (__bf16)ya[r];
    }

    float* outp = out + (size_t)row0 * SEQ * FD;

    // ---------------- 512-step recurrence ----------------
    for (int t = 0; t < SEQ; ++t) {
        __syncthreads();   // barrier A: Z[cur] (h + x) complete; prev dense CB-reads done

        const __bf16* Zc = Zb + (t & 1) * (16 * ZSTR);
        __bf16*       Zn = Zb + ((t + 1) & 1) * (16 * ZSTR);

        // per-lane marching pointer over this wave's 40 chunks; laundered per step so
        // LICM can't hoist the (t-invariant) weight loads out of the t-loop.
        const __bf16* gp = wgbase + l * 8;
        asm volatile("" : "+v"(gp));

        // register double-buffer: group g even -> sA, odd -> sB
        bf16x8 sA[5], sB[5];
#pragma unroll
        for (int c = 0; c < 5; ++c) sA[c] = *(const bf16x8*)(gp + c * 512);
#pragma unroll
        for (int c = 0; c < 5; ++c) sB[c] = *(const bf16x8*)(gp + 2560 + c * 512);

        bf16x8 aph[5];
        f32x4  acc[4];

#pragma unroll
        for (int i = 0; i < 8; ++i) {
            const int h = i >> 2, nt = i & 3;

            // phase start: load the 5 A-frags for this k-half
            if ((i & 3) == 0) {
#pragma unroll
                for (int c = 0; c < 5; ++c)
                    aph[c] = *(const bf16x8*)(&Zc[lr * ZSTR + (h * 5 + c) * 32 + lg * 8]);
            }

            const float bb = biasv[nt];
            f32x4 cc = (h == 0) ? f32x4{bb, bb, bb, bb} : acc[nt];
            if ((i & 1) == 0) {
                cc = __builtin_amdgcn_mfma_f32_16x16x32_bf16(aph[0], sA[0], cc, 0, 0, 0);
                cc = __builtin_amdgcn_mfma_f32_16x16x32_bf16(aph[1], sA[1], cc, 0, 0, 0);
                cc = __builtin_amdgcn_mfma_f32_16x16x32_bf16(aph[2], sA[2], cc, 0, 0, 0);
                cc = __builtin_amdgcn_mfma_f32_16x16x32_bf16(aph[3], sA[3], cc, 0, 0, 0);
                cc = __builtin_amdgcn_mfma_f32_16x16x32_bf16(aph[4], sA[4], cc, 0, 0, 0);
                if (i + 2 < 8) {      // prefetch group i+2 into the buffer just freed
#pragma unroll
                    for (int c = 0; c < 5; ++c)
                        sA[c] = *(const bf16x8*)(gp + (i + 2) * 2560 + c * 512);
                }
            } else {
                cc = __builtin_amdgcn_mfma_f32_16x16x32_bf16(aph[0], sB[0], cc, 0, 0, 0);
                cc = __builtin_amdgcn_mfma_f32_16x16x32_bf16(aph[1], sB[1], cc, 0, 0, 0);
                cc = __builtin_amdgcn_mfma_f32_16x16x32_bf16(aph[2], sB[2], cc, 0, 0, 0);
                cc = __builtin_amdgcn_mfma_f32_16x16x32_bf16(aph[3], sB[3], cc, 0, 0, 0);
                cc = __builtin_amdgcn_mfma_f32_16x16x32_bf16(aph[4], sB[4], cc, 0, 0, 0);
                if (i + 2 < 8) {
#pragma unroll
                    for (int c = 0; c < 5; ++c)
                        sB[c] = *(const bf16x8*)(gp + (i + 2) * 2560 + c * 512);
                }
            }
            acc[nt] = cc;

            if (i == 7) {
                // element-wise LSTM update for this wave's slice
#pragma unroll
                for (int r = 0; r < 4; ++r) {
                    const int m = lg * 4 + r;
                    const float ig = sigm(acc[0][r]);
                    const float fg = sigm(acc[1][r]);
                    const float gg = tanh_(acc[2][r]);
                    const float og = sigm(acc[3][r]);
                    const float cn = fg * creg[r] + ig * gg;
                    creg[r] = cn;
                    const float hn = og * tanh_(cn);
                    Zn[m * ZSTR + 64 + jj] = (__bf16)hn;
                    CBb[m * CSTR + jj]     = (__bf16)cn;
                }
            }
        }

        __syncthreads();   // barrier B: CB ready

        if (w < 4) {
            // y_t = c_new @ W_dense^T + b_dense; dense W re-read from L2 each step
            // (laundered so it can't become a 32-reg resident class).
            const __bf16* wdp = wdbase;
            asm volatile("" : "+v"(wdp));
            f32x4 ya = {ybias, ybias, ybias, ybias};
#pragma unroll
            for (int c = 0; c < 8; ++c) {
                bf16x8 wdc = *(const bf16x8*)(wdp + c * 512);
                bf16x8 acb = *(const bf16x8*)(&CBb[lr * CSTR + c * 32 + lg * 8]);
                ya = __builtin_amdgcn_mfma_f32_16x16x32_bf16(acb, wdc, ya, 0, 0, 0);
            }
            const int f = w * 16 + lr;
#pragma unroll
            for (int r = 0; r < 4; ++r) {
                const int m = lg * 4 + r;
                outp[(size_t)m * (SEQ * FD) + t * FD + f] = ya[r];  // fp32 output
                Zn[m * ZSTR + f] = (__bf16)ya[r];                   // x for next step
            }
        }
    }
}

extern "C" void kernel_launch(void* const* d_in, const int* in_sizes, int n_in,
                              void* d_out, int out_size, void* d_ws, size_t ws_size,
                              hipStream_t stream) {
    (void)in_sizes; (void)n_in; (void)ws_size; (void)out_size;
    const float* h0      = (const float*)d_in[1];
    const float* c0      = (const float*)d_in[2];
    const float* W_ih    = (const float*)d_in[3];
    const float* W_hh    = (const float*)d_in[4];
    const float* b_ih    = (const float*)d_in[5];
    const float* b_hh    = (const float*)d_in[6];
    const float* W_dense = (const float*)d_in[7];
    const float* b_dense = (const float*)d_in[8];
    __bf16* wsb = (__bf16*)d_ws;    // uses 688,128 bytes of workspace

    prep_weights<<<132, 64, 0, stream>>>(W_ih, W_hh, W_dense, wsb);
    lstm_persist<<<128, 1024, 0, stream>>>(h0, c0, b_ih, b_hh, b_dense, wsb, (float*)d_out);
}